// Round 1
// baseline (172.614 us; speedup 1.0000x reference)
//
#include <hip/hip_runtime.h>

#define L_COORD 5.0f
#define L_NOOBJ 0.5f

__device__ __forceinline__ float iou_one(float cx, float cy, float w, float h,
                                         float tx, float ty, float tw, float th) {
    float ax1 = cx - w * 0.5f, ay1 = cy - h * 0.5f;
    float ax2 = cx + w * 0.5f, ay2 = cy + h * 0.5f;
    float bx1 = tx - tw * 0.5f, by1 = ty - th * 0.5f;
    float bx2 = tx + tw * 0.5f, by2 = ty + th * 0.5f;
    float iw = fmaxf(fminf(ax2, bx2) - fmaxf(ax1, bx1), 0.0f);
    float ih = fmaxf(fminf(ay2, by2) - fmaxf(ay1, by1), 0.0f);
    float inter = iw * ih;
    float uni = w * h + tw * th - inter;
    return inter / fmaxf(uni, 1e-10f);
}

__global__ __launch_bounds__(256) void yolo_loss_partial(
    const float* __restrict__ pred, const float* __restrict__ target,
    float* __restrict__ acc, int ncells)
{
    float loc = 0.0f, cobj = 0.0f, cnoobj = 0.0f, clsn = 0.0f, nobj = 0.0f;

    for (int cell = blockIdx.x * blockDim.x + threadIdx.x; cell < ncells;
         cell += gridDim.x * blockDim.x) {
        const float2* p2 = reinterpret_cast<const float2*>(pred) + (size_t)cell * 15;
        const float2* t2 = reinterpret_cast<const float2*>(target) + (size_t)cell * 15;

        float p[30], t[30];
#pragma unroll
        for (int k = 0; k < 15; ++k) {
            float2 v = p2[k];
            p[2 * k] = v.x; p[2 * k + 1] = v.y;
        }
#pragma unroll
        for (int k = 0; k < 15; ++k) {
            float2 v = t2[k];
            t[2 * k] = v.x; t[2 * k + 1] = v.y;
        }

        float objf = (t[4] == 1.0f) ? 1.0f : 0.0f;
        float noobjf = 1.0f - objf;

        // IoU of both predicted boxes vs target box (all compile-time indices)
        float iou0 = iou_one(p[0], p[1], p[2], p[3], t[0], t[1], t[2], t[3]);
        float iou1 = iou_one(p[5], p[6], p[7], p[8], t[0], t[1], t[2], t[3]);

        bool b0 = iou0 > iou1;                 // best == 0
        float wx = b0 ? p[0] : p[5];
        float wy = b0 ? p[1] : p[6];
        float ww = b0 ? p[2] : p[7];
        float whh = b0 ? p[3] : p[8];
        float wc = b0 ? p[4] : p[9];
        float wiou = fmaxf(iou0, iou1);

        float dx = wx - t[0], dy = wy - t[1];
        float xy = dx * dx + dy * dy;
        float dw = sqrtf(ww) - sqrtf(t[2]);
        float dh = sqrtf(whh) - sqrtf(t[3]);
        float wh = dw * dw + dh * dh;
        loc += (xy + wh) * objf;

        float dc = wc - wiou;
        cobj += dc * dc * objf;

        // class CE: log_softmax over p[10..30), pick logit at argmax(target[10..30))
        float m = p[10];
#pragma unroll
        for (int k = 11; k < 30; ++k) m = fmaxf(m, p[k]);
        float s = 0.0f;
#pragma unroll
        for (int k = 10; k < 30; ++k) s += __expf(p[k] - m);

        float tm = t[10];
        float psel = p[10];
#pragma unroll
        for (int k = 11; k < 30; ++k) {
            bool gt = t[k] > tm;               // first-max wins (strict >)
            tm = gt ? t[k] : tm;
            psel = gt ? p[k] : psel;
        }
        float ce = (m + __logf(s)) - psel;     // -log_softmax at class
        clsn += ce * objf;
        nobj += objf;

        float d4 = p[4] - t[4], d9 = p[9] - t[9];
        cnoobj += (d4 * d4 + d9 * d9) * noobjf;
    }

    // 64-lane wave reduction
#pragma unroll
    for (int off = 32; off > 0; off >>= 1) {
        loc    += __shfl_down(loc, off);
        cobj   += __shfl_down(cobj, off);
        cnoobj += __shfl_down(cnoobj, off);
        clsn   += __shfl_down(clsn, off);
        nobj   += __shfl_down(nobj, off);
    }

    __shared__ float sm[4][5];
    int lane = threadIdx.x & 63;
    int wid = threadIdx.x >> 6;
    if (lane == 0) {
        sm[wid][0] = loc; sm[wid][1] = cobj; sm[wid][2] = cnoobj;
        sm[wid][3] = clsn; sm[wid][4] = nobj;
    }
    __syncthreads();
    if (threadIdx.x == 0) {
        float a0 = 0.f, a1 = 0.f, a2 = 0.f, a3 = 0.f, a4 = 0.f;
#pragma unroll
        for (int w = 0; w < 4; ++w) {
            a0 += sm[w][0]; a1 += sm[w][1]; a2 += sm[w][2];
            a3 += sm[w][3]; a4 += sm[w][4];
        }
        atomicAdd(&acc[0], a0);
        atomicAdd(&acc[1], a1);
        atomicAdd(&acc[2], a2);
        atomicAdd(&acc[3], a3);
        atomicAdd(&acc[4], a4);
    }
}

__global__ void yolo_finalize(const float* __restrict__ acc,
                              float* __restrict__ out, float invB)
{
    float loc = acc[0], cobj = acc[1], cnoobj = acc[2], clsum = acc[3], nobj = acc[4];
    float n = fmaxf(nobj, 1.0f);
    float cls = clsum / n;
    float total = (L_COORD * loc + cobj + L_NOOBJ * cnoobj + cls) * invB;
    out[0] = total;
    out[1] = loc;
    out[2] = cobj;
    out[3] = cnoobj;
    out[4] = cls;
}

extern "C" void kernel_launch(void* const* d_in, const int* in_sizes, int n_in,
                              void* d_out, int out_size, void* d_ws, size_t ws_size,
                              hipStream_t stream) {
    const float* pred = (const float*)d_in[0];
    const float* target = (const float*)d_in[1];
    float* out = (float*)d_out;
    float* acc = (float*)d_ws;

    int ncells = in_sizes[0] / 30;          // B*S*S
    int B = ncells / 49;                    // S = 7

    hipMemsetAsync(acc, 0, 5 * sizeof(float), stream);

    int threads = 256;
    int blocks = (ncells + threads - 1) / threads;
    if (blocks > 2048) blocks = 2048;
    yolo_loss_partial<<<blocks, threads, 0, stream>>>(pred, target, acc, ncells);
    yolo_finalize<<<1, 1, 0, stream>>>(acc, out, 1.0f / (float)B);
}